// Round 1
// baseline (380.947 us; speedup 1.0000x reference)
//
#include <hip/hip_runtime.h>
#include <hip/hip_bf16.h>
#include <math.h>

// Problem constants (B=4, S=2048, Hd=1024, h=16, d=64). fp32 in/out per the
// reference; bf16 internally (MFMA) with fp32 accumulation.
#define B_SZ   4
#define S_LEN  2048
#define HD     1024
#define NHEAD  16
#define DHEAD  64
#define N3     3072          // 3*Hd
#define M_ROWS 8192          // B*S

typedef __bf16 bf16_t;
typedef __bf16 bf16x4 __attribute__((ext_vector_type(4)));
typedef __bf16 bf16x8 __attribute__((ext_vector_type(8)));
typedef float  floatx4 __attribute__((ext_vector_type(4)));

__device__ __forceinline__ float bf2f(bf16_t x) { return (float)x; }
__device__ __forceinline__ bf16_t f2bf(float f) { return (bf16_t)f; }  // RNE fptrunc
__device__ __forceinline__ float fexp2(float x) { return __builtin_amdgcn_exp2f(x); }

#define QKSCALE 0.1803368801111204f   // 0.125 * log2(e), folded into K in k1

__device__ __forceinline__ bf16x8 cvt8(const float4 lo, const float4 hi) {
    bf16x8 r;
    r[0] = (bf16_t)lo.x; r[1] = (bf16_t)lo.y; r[2] = (bf16_t)lo.z; r[3] = (bf16_t)lo.w;
    r[4] = (bf16_t)hi.x; r[5] = (bf16_t)hi.y; r[6] = (bf16_t)hi.z; r[7] = (bf16_t)hi.w;
    return r;
}

// ---------------------------------------------------------------------------
// Kernel 1: qkv = X @ W^T + b, fused RoPE on q,k; K pre-scaled by
// 0.125*log2(e) so attn softmax runs in base-2 with no scale mul.
// q,k scattered bf16 [b][h][s][d] (RoPE'd scatter needs [s][d]); V scattered
// TRANSPOSED [b][h][d][s] so the attention PV B-operand is a direct
// contiguous global load (kills the in-LDS V transpose in kernel 2).
// V [d][s] write is also cheaper here: 4 consecutive s per thread collapse
// into one bf16x4 store instead of 8 scalar 2B stores.
// Trig: __cosf/__sinf (hw approx) — outputs truncate to bf16, precision free.
// ---------------------------------------------------------------------------
__global__ __launch_bounds__(256, 3)
void qkv_rope_kernel(const float* __restrict__ X, const float* __restrict__ W,
                     const float* __restrict__ bias,
                     bf16_t* __restrict__ qws, bf16_t* __restrict__ kws,
                     bf16_t* __restrict__ vws)
{
    __shared__ bf16_t As[128 * 32];   // 8 KB, [row][32] bf16 (16-dword rows)
    __shared__ bf16_t Bs[128 * 32];   // 8 KB

    const int tid  = threadIdx.x;
    const int wave = tid >> 6;
    const int lane = tid & 63;
    const int l15  = lane & 15;
    const int quad = lane >> 4;
    const int wm   = wave >> 1;
    const int wn   = wave & 1;
    const int m0   = blockIdx.y * 128;
    const int n0   = blockIdx.x * 128;

    const int b0   = tid;
    const int b1   = tid + 256;
    const int r0   = b0 >> 2, c0 = (b0 & 3) * 8;
    const int r1   = b1 >> 2, c1 = (b1 & 3) * 8;

    const float* gA0 = X + (size_t)(m0 + r0) * HD + c0;
    const float* gA1 = X + (size_t)(m0 + r1) * HD + c1;
    const float* gB0 = W + (size_t)(n0 + r0) * HD + c0;
    const float* gB1 = W + (size_t)(n0 + r1) * HD + c1;

    floatx4 acc[4][4];
#pragma unroll
    for (int i = 0; i < 4; ++i)
#pragma unroll
        for (int j = 0; j < 4; ++j)
            acc[i][j] = (floatx4){0.f, 0.f, 0.f, 0.f};

    float4 a0l = *(const float4*)(gA0);     float4 a0h = *(const float4*)(gA0 + 4);
    float4 a1l = *(const float4*)(gA1);     float4 a1h = *(const float4*)(gA1 + 4);
    float4 w0l = *(const float4*)(gB0);     float4 w0h = *(const float4*)(gB0 + 4);
    float4 w1l = *(const float4*)(gB1);     float4 w1h = *(const float4*)(gB1 + 4);

    for (int kt = 0; kt < 32; ++kt) {
        *(bf16x8*)(As + r0 * 32 + c0) = cvt8(a0l, a0h);
        *(bf16x8*)(As + r1 * 32 + c1) = cvt8(a1l, a1h);
        *(bf16x8*)(Bs + r0 * 32 + c0) = cvt8(w0l, w0h);
        *(bf16x8*)(Bs + r1 * 32 + c1) = cvt8(w1l, w1h);
        __syncthreads();

        if (kt + 1 < 32) {
            const int k0 = (kt + 1) * 32;
            a0l = *(const float4*)(gA0 + k0);  a0h = *(const float4*)(gA0 + k0 + 4);
            a1l = *(const float4*)(gA1 + k0);  a1h = *(const float4*)(gA1 + k0 + 4);
            w0l = *(const float4*)(gB0 + k0);  w0h = *(const float4*)(gB0 + k0 + 4);
            w1l = *(const float4*)(gB1 + k0);  w1h = *(const float4*)(gB1 + k0 + 4);
        }

        bf16x8 af[4], bfr[4];
#pragma unroll
        for (int t = 0; t < 4; ++t) {
            af[t]  = *(const bf16x8*)(As + (wm * 64 + t * 16 + l15) * 32 + quad * 8);
            bfr[t] = *(const bf16x8*)(Bs + (wn * 64 + t * 16 + l15) * 32 + quad * 8);
        }
#pragma unroll
        for (int i = 0; i < 4; ++i)
#pragma unroll
            for (int j = 0; j < 4; ++j)
                acc[i][j] = __builtin_amdgcn_mfma_f32_16x16x32_bf16(
                    af[i], bfr[j], acc[i][j], 0, 0, 0);
        __syncthreads();
    }

    // Epilogue: bias + RoPE + scatter. C/D: col=lane&15, row=quad*4+reg.
    // mrow_base..+3 never cross a 2048 (batch) boundary: hoist bb/sb.
#pragma unroll
    for (int i = 0; i < 4; ++i) {
        const int mrow_base = m0 + wm * 64 + i * 16 + quad * 4;
        const int bb = mrow_base >> 11;
        const int sb = mrow_base & (S_LEN - 1);
#pragma unroll
        for (int j = 0; j < 2; ++j) {
            const int n1 = n0 + wn * 64 + j * 16 + l15;    // dim in [0,32)
            const int n2 = n1 + 32;
            const float b1 = bias[n1];
            const float b2 = bias[n2];
            const int which = n1 >> 10;          // 0=q 1=k 2=v (block-uniform)
            const int hd    = n1 & 1023;
            const int head  = hd >> 6;
            const int dim   = hd & 63;           // < 32 by construction
            if (which == 2) {
                // V: no RoPE; write transposed [b][h][d][s], bf16x4 over r.
                bf16x4 v1, v2;
#pragma unroll
                for (int r = 0; r < 4; ++r) {
                    v1[r] = f2bf(acc[i][j][r]     + b1);
                    v2[r] = f2bf(acc[i][j + 2][r] + b2);
                }
                const size_t off = ((size_t)(bb * NHEAD + head) * DHEAD + dim) * S_LEN + sb;
                *(bf16x4*)(vws + off)                        = v1;
                *(bf16x4*)(vws + off + (size_t)32 * S_LEN)   = v2;
            } else {
                const float inv_freq = __expf(-(float)dim * 0.28782313662425572f);
                bf16_t* outp = (which == 0) ? qws : kws;
#pragma unroll
                for (int r = 0; r < 4; ++r) {
                    const int s = sb + r;
                    float x1 = acc[i][j][r]     + b1;
                    float x2 = acc[i][j + 2][r] + b2;
                    const float ang = (float)s * inv_freq;
                    float cs = __cosf(ang);
                    float sn = __sinf(ang);
                    if (which == 1) { cs *= QKSCALE; sn *= QKSCALE; }
                    const float o1 = x1 * cs - x2 * sn;
                    const float o2 = x2 * cs + x1 * sn;
                    const size_t off = ((size_t)(bb * NHEAD + head) * S_LEN + s) * DHEAD + dim;
                    outp[off]      = f2bf(o1);
                    outp[off + 32] = f2bf(o2);
                }
            }
        }
    }
}

// ---------------------------------------------------------------------------
// Kernel 2: flash attention, operand-swapped QK^T (S^T = K Q^T): lane owns
// one q-row -> softmax = local max/sum + xor16/xor32 shuffles only. P written
// t-contiguous b64 into [q][t] stride-72 wave-private slab, read b128.
// V is consumed DIRECTLY from global V^T [b][h][d][s] (written by k1):
// the PV B-fragment (lane: n=d, k=t contiguous) is one aligned 16B global
// load, L2-resident (grid pins all 16 q-tiles of a bh to one XCD; V per bh
// = 256 KB << 4 MB L2). This removes the Vt LDS slab, the 16 scalar
// ds_write_b16 transpose, 8 ds_read_b128, and the V prefetch registers:
// LDS traffic/wave-iter drops ~28.5KB -> ~18KB on the CU-shared LDS pipe.
// K pre-scaled in k1 -> base-2 softmax, no muls. grid=(bh,qt) XCD locality.
// __launch_bounds__(256,3): (256,4) forced a 64-VGPR budget ->
// per-iteration scratch spill (WRITE_SIZE 294 MB). 3 waves/EU = 170 cap.
// ---------------------------------------------------------------------------
#define STK 72
#define STP 72

__global__ __launch_bounds__(256, 3)
void attn_kernel(const bf16_t* __restrict__ qws, const bf16_t* __restrict__ kws,
                 const bf16_t* __restrict__ vtws, float* __restrict__ out)
{
    __shared__ bf16_t Ks[64 * STK];    // 9216 B  K [t][d]
    __shared__ bf16_t Ps[128 * STP];   // 18432 B P [q][t], wave-private rows

    const int tid  = threadIdx.x;
    const int wave = tid >> 6;
    const int lane = tid & 63;
    const int l15  = lane & 15;
    const int quad = lane >> 4;
    const int bh   = blockIdx.x;          // 0..63  (XCD = bh % 8)
    const int qt   = blockIdx.y;          // 0..15
    const size_t baseS = (size_t)bh * S_LEN * DHEAD;   // q/k [s][d]; vt [d][s]
    const int q0 = qt * 128 + wave * 32;

    // Q fragments (B-operand: n=q on lane&15, k=d on quad*8+j), persistent.
    bf16x8 aq[2][2];
#pragma unroll
    for (int qsub = 0; qsub < 2; ++qsub)
#pragma unroll
        for (int kb = 0; kb < 2; ++kb)
            aq[qsub][kb] = *(const bf16x8*)(qws + baseS +
                (size_t)(q0 + qsub * 16 + l15) * DHEAD + kb * 32 + quad * 8);

    // K staging coords: 64 t-rows x 64 d-cols, 2 x uint4 per thread
    const int srow = tid >> 2;            // t
    const int scol = (tid & 3) * 8;       // d base

    uint4 kreg[2];
#pragma unroll
    for (int jj = 0; jj < 2; ++jj)
        kreg[jj] = *(const uint4*)(kws + baseS + (size_t)srow * DHEAD + scol + jj * 32);

    float m_i[2] = {-1e30f, -1e30f};      // per-lane state for q = qsub*16+l15
    float l_i[2] = {0.f, 0.f};            // (replicated across quads)
    floatx4 o_acc[2][4];
#pragma unroll
    for (int qsub = 0; qsub < 2; ++qsub)
#pragma unroll
        for (int dt = 0; dt < 4; ++dt)
            o_acc[qsub][dt] = (floatx4){0.f, 0.f, 0.f, 0.f};

    for (int kt = 0; kt < 32; ++kt) {
        // --- stage K row-major ---------------------------------------------
#pragma unroll
        for (int jj = 0; jj < 2; ++jj)
            *(uint4*)(Ks + srow * STK + scol + jj * 32) = kreg[jj];
        __syncthreads();

        // prefetch next K tile
        if (kt + 1 < 32) {
            const int t0 = (kt + 1) * 64;
#pragma unroll
            for (int jj = 0; jj < 2; ++jj)
                kreg[jj] = *(const uint4*)(kws + baseS + (size_t)(t0 + srow) * DHEAD + scol + jj * 32);
        }

        // --- S^T = K Q^T : C row = t (quad*4+r), col = q (l15) -------------
        floatx4 st[2][4];
#pragma unroll
        for (int qsub = 0; qsub < 2; ++qsub)
#pragma unroll
            for (int mt = 0; mt < 4; ++mt)
                st[qsub][mt] = (floatx4){0.f, 0.f, 0.f, 0.f};
#pragma unroll
        for (int kb = 0; kb < 2; ++kb)
#pragma unroll
            for (int mt = 0; mt < 4; ++mt) {
                bf16x8 ak = *(const bf16x8*)(Ks + (mt * 16 + l15) * STK + kb * 32 + quad * 8);
#pragma unroll
                for (int qsub = 0; qsub < 2; ++qsub)
                    st[qsub][mt] = __builtin_amdgcn_mfma_f32_16x16x32_bf16(
                        ak, aq[qsub][kb], st[qsub][mt], 0, 0, 0);
            }

        // --- online softmax: lane owns q = qsub*16+l15, 16 t-values local --
        float alphaL[2];
#pragma unroll
        for (int qsub = 0; qsub < 2; ++qsub) {
            float mx = st[qsub][0][0];
#pragma unroll
            for (int mt = 0; mt < 4; ++mt)
#pragma unroll
                for (int r = 0; r < 4; ++r)
                    mx = fmaxf(mx, st[qsub][mt][r]);
            mx = fmaxf(mx, __shfl_xor(mx, 16, 64));
            mx = fmaxf(mx, __shfl_xor(mx, 32, 64));
            const float mnew = fmaxf(m_i[qsub], mx);
            alphaL[qsub] = fexp2(m_i[qsub] - mnew);
            float rs = 0.f;
#pragma unroll
            for (int mt = 0; mt < 4; ++mt) {
                bf16x4 pb;
#pragma unroll
                for (int r = 0; r < 4; ++r) {
                    const float p = fexp2(st[qsub][mt][r] - mnew);
                    pb[r] = f2bf(p);
                    rs += bf2f(pb[r]);
                }
                *(bf16x4*)(Ps + (wave * 32 + qsub * 16 + l15) * STP + mt * 16 + quad * 4) = pb;
            }
            rs += __shfl_xor(rs, 16, 64);
            rs += __shfl_xor(rs, 32, 64);
            l_i[qsub] = l_i[qsub] * alphaL[qsub] + rs;
            m_i[qsub] = mnew;
        }

        // --- V fragments straight from global V^T (st[] regs dead now) -----
        // B-operand: n=d on l15 (+dt*16), k=t on quad*8+j (+kb*32): 16B each.
        bf16x8 bv[2][4];
#pragma unroll
        for (int kb = 0; kb < 2; ++kb)
#pragma unroll
            for (int dt = 0; dt < 4; ++dt)
                bv[kb][dt] = *(const bf16x8*)(vtws + baseS +
                    (size_t)(dt * 16 + l15) * S_LEN + kt * 64 + kb * 32 + quad * 8);

        // --- rescale O (alpha moved to C-layout rows via one shfl per r) ---
#pragma unroll
        for (int qsub = 0; qsub < 2; ++qsub)
#pragma unroll
            for (int r = 0; r < 4; ++r) {
                const float a = __shfl(alphaL[qsub], (lane & 48) | (quad * 4 + r), 64);
#pragma unroll
                for (int dt = 0; dt < 4; ++dt)
                    o_acc[qsub][dt][r] *= a;
            }

        // --- O += P V : A = P [q][t] (b128), B = V^T fragments (global) ----
#pragma unroll
        for (int kb = 0; kb < 2; ++kb) {
#pragma unroll
            for (int qsub = 0; qsub < 2; ++qsub) {
                bf16x8 ap = *(const bf16x8*)(Ps + (wave * 32 + qsub * 16 + l15) * STP + kb * 32 + quad * 8);
#pragma unroll
                for (int dt = 0; dt < 4; ++dt)
                    o_acc[qsub][dt] = __builtin_amdgcn_mfma_f32_16x16x32_bf16(
                        ap, bv[kb][dt], o_acc[qsub][dt], 0, 0, 0);
            }
        }
        __syncthreads();
    }

    // normalize + store out[b][s][h*64+d] (fp32); l transposed via shfl
    const int bb = bh >> 4, hh = bh & 15;
#pragma unroll
    for (int qsub = 0; qsub < 2; ++qsub)
#pragma unroll
        for (int r = 0; r < 4; ++r) {
            const float lv  = __shfl(l_i[qsub], (lane & 48) | (quad * 4 + r), 64);
            const float inv = 1.0f / lv;
            const int s = q0 + qsub * 16 + quad * 4 + r;
            const size_t off0 = ((size_t)(bb * S_LEN + s)) * HD + hh * DHEAD;
#pragma unroll
            for (int dt = 0; dt < 4; ++dt)
                out[off0 + dt * 16 + l15] = o_acc[qsub][dt][r] * inv;
        }
}

extern "C" void kernel_launch(void* const* d_in, const int* in_sizes, int n_in,
                              void* d_out, int out_size, void* d_ws, size_t ws_size,
                              hipStream_t stream) {
    const float* X    = (const float*)d_in[0];   // (4,2048,1024) fp32
    const float* W    = (const float*)d_in[1];   // (3072,1024) fp32
    const float* bias = (const float*)d_in[2];   // (3072,) fp32
    float* out = (float*)d_out;                  // (4,2048,1024) fp32

    const size_t per = (size_t)B_SZ * NHEAD * S_LEN * DHEAD;   // 8.39M elems
    bf16_t* qws = (bf16_t*)d_ws;
    bf16_t* kws = qws + per;
    bf16_t* vws = kws + per;                     // holds V^T [b][h][d][s]

    qkv_rope_kernel<<<dim3(N3 / 128, M_ROWS / 128), 256, 0, stream>>>(
        X, W, bias, qws, kws, vws);
    attn_kernel<<<dim3(B_SZ * NHEAD, S_LEN / 128), 256, 0, stream>>>(
        qws, kws, vws, out);
}

// Round 2
// 359.270 us; speedup vs baseline: 1.0603x; 1.0603x over previous
//
#include <hip/hip_runtime.h>
#include <hip/hip_bf16.h>
#include <math.h>

// Problem constants (B=4, S=2048, Hd=1024, h=16, d=64). fp32 in/out per the
// reference; bf16 internally (MFMA) with fp32 accumulation.
#define B_SZ   4
#define S_LEN  2048
#define HD     1024
#define NHEAD  16
#define DHEAD  64
#define N3     3072          // 3*Hd
#define M_ROWS 8192          // B*S

typedef __bf16 bf16_t;
typedef __bf16 bf16x4 __attribute__((ext_vector_type(4)));
typedef __bf16 bf16x8 __attribute__((ext_vector_type(8)));
typedef float  floatx4 __attribute__((ext_vector_type(4)));

__device__ __forceinline__ float bf2f(bf16_t x) { return (float)x; }
__device__ __forceinline__ bf16_t f2bf(float f) { return (bf16_t)f; }  // RNE fptrunc
__device__ __forceinline__ float fexp2(float x) { return __builtin_amdgcn_exp2f(x); }

__device__ __forceinline__ floatx4 fmax4(floatx4 a, floatx4 b) {
    floatx4 r;
    r[0] = fmaxf(a[0], b[0]); r[1] = fmaxf(a[1], b[1]);
    r[2] = fmaxf(a[2], b[2]); r[3] = fmaxf(a[3], b[3]);
    return r;
}

#define QKSCALE 0.1803368801111204f   // 0.125 * log2(e), folded into K in k1

__device__ __forceinline__ bf16x8 cvt8(const float4 lo, const float4 hi) {
    bf16x8 r;
    r[0] = (bf16_t)lo.x; r[1] = (bf16_t)lo.y; r[2] = (bf16_t)lo.z; r[3] = (bf16_t)lo.w;
    r[4] = (bf16_t)hi.x; r[5] = (bf16_t)hi.y; r[6] = (bf16_t)hi.z; r[7] = (bf16_t)hi.w;
    return r;
}

// ---------------------------------------------------------------------------
// Kernel 1 (unchanged this round): qkv = X @ W^T + b, fused RoPE on q,k; K
// pre-scaled by 0.125*log2(e) so attn softmax runs base-2. q,k scattered
// bf16 [b][h][s][d]; V scattered transposed [b][h][d][s] for k2's direct
// global PV B-operand loads.
// ---------------------------------------------------------------------------
__global__ __launch_bounds__(256, 3)
void qkv_rope_kernel(const float* __restrict__ X, const float* __restrict__ W,
                     const float* __restrict__ bias,
                     bf16_t* __restrict__ qws, bf16_t* __restrict__ kws,
                     bf16_t* __restrict__ vws)
{
    __shared__ bf16_t As[128 * 32];   // 8 KB, [row][32] bf16 (16-dword rows)
    __shared__ bf16_t Bs[128 * 32];   // 8 KB

    const int tid  = threadIdx.x;
    const int wave = tid >> 6;
    const int lane = tid & 63;
    const int l15  = lane & 15;
    const int quad = lane >> 4;
    const int wm   = wave >> 1;
    const int wn   = wave & 1;
    const int m0   = blockIdx.y * 128;
    const int n0   = blockIdx.x * 128;

    const int b0   = tid;
    const int b1   = tid + 256;
    const int r0   = b0 >> 2, c0 = (b0 & 3) * 8;
    const int r1   = b1 >> 2, c1 = (b1 & 3) * 8;

    const float* gA0 = X + (size_t)(m0 + r0) * HD + c0;
    const float* gA1 = X + (size_t)(m0 + r1) * HD + c1;
    const float* gB0 = W + (size_t)(n0 + r0) * HD + c0;
    const float* gB1 = W + (size_t)(n0 + r1) * HD + c1;

    floatx4 acc[4][4];
#pragma unroll
    for (int i = 0; i < 4; ++i)
#pragma unroll
        for (int j = 0; j < 4; ++j)
            acc[i][j] = (floatx4){0.f, 0.f, 0.f, 0.f};

    float4 a0l = *(const float4*)(gA0);     float4 a0h = *(const float4*)(gA0 + 4);
    float4 a1l = *(const float4*)(gA1);     float4 a1h = *(const float4*)(gA1 + 4);
    float4 w0l = *(const float4*)(gB0);     float4 w0h = *(const float4*)(gB0 + 4);
    float4 w1l = *(const float4*)(gB1);     float4 w1h = *(const float4*)(gB1 + 4);

    for (int kt = 0; kt < 32; ++kt) {
        *(bf16x8*)(As + r0 * 32 + c0) = cvt8(a0l, a0h);
        *(bf16x8*)(As + r1 * 32 + c1) = cvt8(a1l, a1h);
        *(bf16x8*)(Bs + r0 * 32 + c0) = cvt8(w0l, w0h);
        *(bf16x8*)(Bs + r1 * 32 + c1) = cvt8(w1l, w1h);
        __syncthreads();

        if (kt + 1 < 32) {
            const int k0 = (kt + 1) * 32;
            a0l = *(const float4*)(gA0 + k0);  a0h = *(const float4*)(gA0 + k0 + 4);
            a1l = *(const float4*)(gA1 + k0);  a1h = *(const float4*)(gA1 + k0 + 4);
            w0l = *(const float4*)(gB0 + k0);  w0h = *(const float4*)(gB0 + k0 + 4);
            w1l = *(const float4*)(gB1 + k0);  w1h = *(const float4*)(gB1 + k0 + 4);
        }

        bf16x8 af[4], bfr[4];
#pragma unroll
        for (int t = 0; t < 4; ++t) {
            af[t]  = *(const bf16x8*)(As + (wm * 64 + t * 16 + l15) * 32 + quad * 8);
            bfr[t] = *(const bf16x8*)(Bs + (wn * 64 + t * 16 + l15) * 32 + quad * 8);
        }
#pragma unroll
        for (int i = 0; i < 4; ++i)
#pragma unroll
            for (int j = 0; j < 4; ++j)
                acc[i][j] = __builtin_amdgcn_mfma_f32_16x16x32_bf16(
                    af[i], bfr[j], acc[i][j], 0, 0, 0);
        __syncthreads();
    }

    // Epilogue: bias + RoPE + scatter. C/D: col=lane&15, row=quad*4+reg.
    // mrow_base..+3 never cross a 2048 (batch) boundary: hoist bb/sb.
#pragma unroll
    for (int i = 0; i < 4; ++i) {
        const int mrow_base = m0 + wm * 64 + i * 16 + quad * 4;
        const int bb = mrow_base >> 11;
        const int sb = mrow_base & (S_LEN - 1);
#pragma unroll
        for (int j = 0; j < 2; ++j) {
            const int n1 = n0 + wn * 64 + j * 16 + l15;    // dim in [0,32)
            const int n2 = n1 + 32;
            const float b1 = bias[n1];
            const float b2 = bias[n2];
            const int which = n1 >> 10;          // 0=q 1=k 2=v (block-uniform)
            const int hd    = n1 & 1023;
            const int head  = hd >> 6;
            const int dim   = hd & 63;           // < 32 by construction
            if (which == 2) {
                // V: no RoPE; write transposed [b][h][d][s], bf16x4 over r.
                bf16x4 v1, v2;
#pragma unroll
                for (int r = 0; r < 4; ++r) {
                    v1[r] = f2bf(acc[i][j][r]     + b1);
                    v2[r] = f2bf(acc[i][j + 2][r] + b2);
                }
                const size_t off = ((size_t)(bb * NHEAD + head) * DHEAD + dim) * S_LEN + sb;
                *(bf16x4*)(vws + off)                        = v1;
                *(bf16x4*)(vws + off + (size_t)32 * S_LEN)   = v2;
            } else {
                const float inv_freq = __expf(-(float)dim * 0.28782313662425572f);
                bf16_t* outp = (which == 0) ? qws : kws;
#pragma unroll
                for (int r = 0; r < 4; ++r) {
                    const int s = sb + r;
                    float x1 = acc[i][j][r]     + b1;
                    float x2 = acc[i][j + 2][r] + b2;
                    const float ang = (float)s * inv_freq;
                    float cs = __cosf(ang);
                    float sn = __sinf(ang);
                    if (which == 1) { cs *= QKSCALE; sn *= QKSCALE; }
                    const float o1 = x1 * cs - x2 * sn;
                    const float o2 = x2 * cs + x1 * sn;
                    const size_t off = ((size_t)(bb * NHEAD + head) * S_LEN + s) * DHEAD + dim;
                    outp[off]      = f2bf(o1);
                    outp[off + 32] = f2bf(o2);
                }
            }
        }
    }
}

// ---------------------------------------------------------------------------
// Kernel 2: flash attention, operand-swapped QK^T (S^T = K Q^T).
// Round-1 counters: MfmaUtil 13.5 / VALUBusy 33 / HBM 4.6% -> latency-bound.
// Fixes this round:
//  * bv (PV B-operand, global V^T) issued at TOP of iter -> ~300cy of
//    QK+stage+softmax covers the L2 round trip before PV consumes them.
//  * Ks double-buffered -> ONE barrier per iteration (was 2); K global
//    prefetch now has a full iteration in flight.
//  * tree max-reduce (depth ~5 vs serial 16-chain).
//  * defer-rescale (THR=8, base-2): when __all(mx - m_i <= 8) keep old max;
//    skips alpha-transpose shfl storm + 32 muls (wave-uniform branch).
// __launch_bounds__(256,3): (256,4) forced 64-VGPR budget -> spill.
// ---------------------------------------------------------------------------
#define STK 72
#define STP 72

__global__ __launch_bounds__(256, 3)
void attn_kernel(const bf16_t* __restrict__ qws, const bf16_t* __restrict__ kws,
                 const bf16_t* __restrict__ vtws, float* __restrict__ out)
{
    __shared__ bf16_t Ks[2][64 * STK]; // 2 x 9216 B  K [t][d], double-buffered
    __shared__ bf16_t Ps[128 * STP];   // 18432 B P [q][t], wave-private rows

    const int tid  = threadIdx.x;
    const int wave = tid >> 6;
    const int lane = tid & 63;
    const int l15  = lane & 15;
    const int quad = lane >> 4;
    const int bh   = blockIdx.x;          // 0..63  (XCD = bh % 8)
    const int qt   = blockIdx.y;          // 0..15
    const size_t baseS = (size_t)bh * S_LEN * DHEAD;   // q/k [s][d]; vt [d][s]
    const int q0 = qt * 128 + wave * 32;

    // Q fragments (B-operand: n=q on lane&15, k=d on quad*8+j), persistent.
    bf16x8 aq[2][2];
#pragma unroll
    for (int qsub = 0; qsub < 2; ++qsub)
#pragma unroll
        for (int kb = 0; kb < 2; ++kb)
            aq[qsub][kb] = *(const bf16x8*)(qws + baseS +
                (size_t)(q0 + qsub * 16 + l15) * DHEAD + kb * 32 + quad * 8);

    // K staging coords: 64 t-rows x 64 d-cols, 2 x uint4 per thread
    const int srow = tid >> 2;            // t
    const int scol = (tid & 3) * 8;       // d base
    const bf16_t* kstage = kws + baseS + (size_t)srow * DHEAD + scol;
    const bf16_t* vtbase = vtws + baseS + quad * 8;

    // Prologue: tile 0 -> Ks[0]; tile 1 -> kreg; one barrier.
    uint4 kreg[2];
#pragma unroll
    for (int jj = 0; jj < 2; ++jj)
        kreg[jj] = *(const uint4*)(kstage + jj * 32);
#pragma unroll
    for (int jj = 0; jj < 2; ++jj)
        *(uint4*)(&Ks[0][0] + srow * STK + scol + jj * 32) = kreg[jj];
#pragma unroll
    for (int jj = 0; jj < 2; ++jj)
        kreg[jj] = *(const uint4*)(kstage + 64 * DHEAD + jj * 32);
    __syncthreads();

    float m_i[2] = {-1e30f, -1e30f};      // per-lane state for q = qsub*16+l15
    float l_i[2] = {0.f, 0.f};            // (replicated across quads)
    floatx4 o_acc[2][4];
#pragma unroll
    for (int qsub = 0; qsub < 2; ++qsub)
#pragma unroll
        for (int dt = 0; dt < 4; ++dt)
            o_acc[qsub][dt] = (floatx4){0.f, 0.f, 0.f, 0.f};

    for (int kt = 0; kt < 32; ++kt) {
        const int cur = kt & 1;

        // --- V fragments for THIS iter: issue first, consume at PV ---------
        // B-operand: n=d on l15 (+dt*16), k=t on quad*8+j (+kb*32): 16B each.
        bf16x8 bv[2][4];
#pragma unroll
        for (int kb = 0; kb < 2; ++kb)
#pragma unroll
            for (int dt = 0; dt < 4; ++dt)
                bv[kb][dt] = *(const bf16x8*)(vtbase +
                    (size_t)(dt * 16 + l15) * S_LEN + kt * 64 + kb * 32);

        // --- S^T = K Q^T : C row = t (quad*4+r), col = q (l15) -------------
        floatx4 st[2][4];
#pragma unroll
        for (int qsub = 0; qsub < 2; ++qsub)
#pragma unroll
            for (int mt = 0; mt < 4; ++mt)
                st[qsub][mt] = (floatx4){0.f, 0.f, 0.f, 0.f};
#pragma unroll
        for (int kb = 0; kb < 2; ++kb)
#pragma unroll
            for (int mt = 0; mt < 4; ++mt) {
                bf16x8 ak = *(const bf16x8*)(&Ks[cur][0] + (mt * 16 + l15) * STK + kb * 32 + quad * 8);
#pragma unroll
                for (int qsub = 0; qsub < 2; ++qsub)
                    st[qsub][mt] = __builtin_amdgcn_mfma_f32_16x16x32_bf16(
                        ak, aq[qsub][kb], st[qsub][mt], 0, 0, 0);
            }

        // --- stage tile kt+1 into other buffer; prefetch tile kt+2 ---------
        if (kt + 1 < 32) {
#pragma unroll
            for (int jj = 0; jj < 2; ++jj)
                *(uint4*)(&Ks[cur ^ 1][0] + srow * STK + scol + jj * 32) = kreg[jj];
            if (kt + 2 < 32) {
#pragma unroll
                for (int jj = 0; jj < 2; ++jj)
                    kreg[jj] = *(const uint4*)(kstage + (size_t)(kt + 2) * 64 * DHEAD + jj * 32);
            }
        }

        // --- online softmax: lane owns q = qsub*16+l15, 16 t-values local --
#pragma unroll
        for (int qsub = 0; qsub < 2; ++qsub) {
            floatx4 m01 = fmax4(st[qsub][0], st[qsub][1]);
            floatx4 m23 = fmax4(st[qsub][2], st[qsub][3]);
            floatx4 mm  = fmax4(m01, m23);
            float mx = fmaxf(fmaxf(mm[0], mm[1]), fmaxf(mm[2], mm[3]));
            mx = fmaxf(mx, __shfl_xor(mx, 16, 64));
            mx = fmaxf(mx, __shfl_xor(mx, 32, 64));

            // defer-rescale: keep old running max while growth <= 8 (base-2
            // units -> P bounded by 2^8 = 256, fine in bf16/f32). First iter
            // always rescales (m_i = -1e30). Wave-uniform branch via __all.
            const bool noresc = __all(mx - m_i[qsub] <= 8.0f) != 0;
            float mref, alpha;
            if (noresc) {
                mref = m_i[qsub];
            } else {
                mref = fmaxf(m_i[qsub], mx);
                alpha = fexp2(m_i[qsub] - mref);
                m_i[qsub] = mref;
            }

            float rs = 0.f;
#pragma unroll
            for (int mt = 0; mt < 4; ++mt) {
                bf16x4 pb;
#pragma unroll
                for (int r = 0; r < 4; ++r) {
                    const float p = fexp2(st[qsub][mt][r] - mref);
                    pb[r] = f2bf(p);
                    rs += bf2f(pb[r]);
                }
                *(bf16x4*)(Ps + (wave * 32 + qsub * 16 + l15) * STP + mt * 16 + quad * 4) = pb;
            }
            rs += __shfl_xor(rs, 16, 64);
            rs += __shfl_xor(rs, 32, 64);

            if (noresc) {
                l_i[qsub] += rs;
            } else {
                l_i[qsub] = l_i[qsub] * alpha + rs;
                // rescale O: alpha moved to C-layout rows via one shfl per r
#pragma unroll
                for (int r = 0; r < 4; ++r) {
                    const float a = __shfl(alpha, (lane & 48) | (quad * 4 + r), 64);
#pragma unroll
                    for (int dt = 0; dt < 4; ++dt)
                        o_acc[qsub][dt][r] *= a;
                }
            }
        }

        // --- O += P V : A = P [q][t] (b128), B = V^T fragments (global) ----
#pragma unroll
        for (int kb = 0; kb < 2; ++kb) {
#pragma unroll
            for (int qsub = 0; qsub < 2; ++qsub) {
                bf16x8 ap = *(const bf16x8*)(Ps + (wave * 32 + qsub * 16 + l15) * STP + kb * 32 + quad * 8);
#pragma unroll
                for (int dt = 0; dt < 4; ++dt)
                    o_acc[qsub][dt] = __builtin_amdgcn_mfma_f32_16x16x32_bf16(
                        ap, bv[kb][dt], o_acc[qsub][dt], 0, 0, 0);
            }
        }
        if (kt + 1 < 32) __syncthreads();
    }

    // normalize + store out[b][s][h*64+d] (fp32); l transposed via shfl
    const int bb = bh >> 4, hh = bh & 15;
#pragma unroll
    for (int qsub = 0; qsub < 2; ++qsub)
#pragma unroll
        for (int r = 0; r < 4; ++r) {
            const float lv  = __shfl(l_i[qsub], (lane & 48) | (quad * 4 + r), 64);
            const float inv = 1.0f / lv;
            const int s = q0 + qsub * 16 + quad * 4 + r;
            const size_t off0 = ((size_t)(bb * S_LEN + s)) * HD + hh * DHEAD;
#pragma unroll
            for (int dt = 0; dt < 4; ++dt)
                out[off0 + dt * 16 + l15] = o_acc[qsub][dt][r] * inv;
        }
}

extern "C" void kernel_launch(void* const* d_in, const int* in_sizes, int n_in,
                              void* d_out, int out_size, void* d_ws, size_t ws_size,
                              hipStream_t stream) {
    const float* X    = (const float*)d_in[0];   // (4,2048,1024) fp32
    const float* W    = (const float*)d_in[1];   // (3072,1024) fp32
    const float* bias = (const float*)d_in[2];   // (3072,) fp32
    float* out = (float*)d_out;                  // (4,2048,1024) fp32

    const size_t per = (size_t)B_SZ * NHEAD * S_LEN * DHEAD;   // 8.39M elems
    bf16_t* qws = (bf16_t*)d_ws;
    bf16_t* kws = qws + per;
    bf16_t* vws = kws + per;                     // holds V^T [b][h][d][s]

    qkv_rope_kernel<<<dim3(N3 / 128, M_ROWS / 128), 256, 0, stream>>>(
        X, W, bias, qws, kws, vws);
    attn_kernel<<<dim3(B_SZ * NHEAD, S_LEN / 128), 256, 0, stream>>>(
        qws, kws, vws, out);
}

// Round 3
// 324.977 us; speedup vs baseline: 1.1722x; 1.1055x over previous
//
#include <hip/hip_runtime.h>
#include <hip/hip_bf16.h>
#include <math.h>

// Problem constants (B=4, S=2048, Hd=1024, h=16, d=64). fp32 in/out per the
// reference; bf16 internally (MFMA) with fp32 accumulation.
#define B_SZ   4
#define S_LEN  2048
#define HD     1024
#define NHEAD  16
#define DHEAD  64
#define N3     3072          // 3*Hd
#define M_ROWS 8192          // B*S

typedef __bf16 bf16_t;
typedef __bf16 bf16x4 __attribute__((ext_vector_type(4)));
typedef __bf16 bf16x8 __attribute__((ext_vector_type(8)));
typedef float  floatx4 __attribute__((ext_vector_type(4)));

__device__ __forceinline__ float bf2f(bf16_t x) { return (float)x; }
__device__ __forceinline__ bf16_t f2bf(float f) { return (bf16_t)f; }  // RNE fptrunc
__device__ __forceinline__ float fexp2(float x) { return __builtin_amdgcn_exp2f(x); }

__device__ __forceinline__ floatx4 fmax4(floatx4 a, floatx4 b) {
    floatx4 r;
    r[0] = fmaxf(a[0], b[0]); r[1] = fmaxf(a[1], b[1]);
    r[2] = fmaxf(a[2], b[2]); r[3] = fmaxf(a[3], b[3]);
    return r;
}

#define QKSCALE 0.1803368801111204f   // 0.125 * log2(e), folded into K in k1

__device__ __forceinline__ bf16x8 cvt8(const float4 lo, const float4 hi) {
    bf16x8 r;
    r[0] = (bf16_t)lo.x; r[1] = (bf16_t)lo.y; r[2] = (bf16_t)lo.z; r[3] = (bf16_t)lo.w;
    r[4] = (bf16_t)hi.x; r[5] = (bf16_t)hi.y; r[6] = (bf16_t)hi.z; r[7] = (bf16_t)hi.w;
    return r;
}

// async 16B global -> LDS (dest = wave-uniform base + lane*16)
__device__ __forceinline__ void gload_lds16(const bf16_t* g, bf16_t* l) {
    __builtin_amdgcn_global_load_lds(
        (const __attribute__((address_space(1))) void*)g,
        (__attribute__((address_space(3))) void*)l, 16, 0, 0);
}

// ---------------------------------------------------------------------------
// Kernel 0 (new): one-shot fp32 -> bf16 convert of X and W, so the GEMM can
// stage with global_load_lds (no dtype conversion possible there). Scratch
// lives in the OUT buffer (23.1 MB <= 33.5 MB); out is only truly written by
// the attn kernel, which runs after the GEMM has consumed Xb/Wb (stream
// serializes). ~69 MB of traffic ≈ 14 us.
// ---------------------------------------------------------------------------
#define NXELEM (M_ROWS * HD)      // 8388608
#define NWELEM (N3 * HD)          // 3145728

__global__ __launch_bounds__(256)
void cvt_kernel(const float* __restrict__ X, const float* __restrict__ W,
                bf16_t* __restrict__ Xb, bf16_t* __restrict__ Wb)
{
    const size_t i = ((size_t)blockIdx.x * 256 + threadIdx.x) * 8;
    if (i < (size_t)NXELEM) {
        float4 lo = *(const float4*)(X + i);
        float4 hi = *(const float4*)(X + i + 4);
        *(bf16x8*)(Xb + i) = cvt8(lo, hi);
    }
    if (i < (size_t)NWELEM) {
        float4 lo = *(const float4*)(W + i);
        float4 hi = *(const float4*)(W + i + 4);
        *(bf16x8*)(Wb + i) = cvt8(lo, hi);
    }
}

// ---------------------------------------------------------------------------
// Kernel 1 (rewritten): bf16 GEMM qkv = Xb @ Wb^T + b with global_load_lds
// staging (m97 structure: 128x128 tile, BK=32, 4 issues/thread/iter, 2
// barriers). Round-2 counters put the fp32-staging version at ~310 TF
// (VALU-bound on load+cvt+ds_write); this removes the whole VALU staging
// path. Fused RoPE epilogue unchanged: K pre-scaled by 0.125*log2(e), q,k
// scattered bf16 [b][h][s][d], V scattered transposed [b][h][d][s].
// Natural grid->XCD map (bx%8; gridDim.x=24 so by doesn't change XCD) gives
// per-XCD W-panel locality already.
// ---------------------------------------------------------------------------
__global__ __launch_bounds__(256, 3)
void qkv_gemm_kernel(const bf16_t* __restrict__ Xb, const bf16_t* __restrict__ Wb,
                     const float* __restrict__ bias,
                     bf16_t* __restrict__ qws, bf16_t* __restrict__ kws,
                     bf16_t* __restrict__ vws)
{
    __shared__ bf16_t As[128 * 32];   // 8 KB, [row][32] bf16, linear
    __shared__ bf16_t Bs[128 * 32];   // 8 KB

    const int tid  = threadIdx.x;
    const int wave = tid >> 6;
    const int lane = tid & 63;
    const int l15  = lane & 15;
    const int quad = lane >> 4;
    const int wm   = wave >> 1;
    const int wn   = wave & 1;
    const int m0   = blockIdx.y * 128;
    const int n0   = blockIdx.x * 128;

    // global_load_lds geometry: wave w covers tile bytes [w*2048, w*2048+2048)
    // in two 1KB issues; lane l writes LDS byte base+l*16 -> tile row
    // w*32 + t*16 + l/4, col (l&3)*8. Global src mirrors that.
    const int rowL = wave * 32 + (lane >> 2);   // + t*16
    const int colL = (lane & 3) * 8;
    const bf16_t* gA = Xb + (size_t)(m0 + rowL) * HD + colL;
    const bf16_t* gB = Wb + (size_t)(n0 + rowL) * HD + colL;
    bf16_t* lA = As + wave * 1024;              // elems; +512 for t=1
    bf16_t* lB = Bs + wave * 1024;

    floatx4 acc[4][4];
#pragma unroll
    for (int i = 0; i < 4; ++i)
#pragma unroll
        for (int j = 0; j < 4; ++j)
            acc[i][j] = (floatx4){0.f, 0.f, 0.f, 0.f};

    for (int kt = 0; kt < 32; ++kt) {
        const int k0 = kt * 32;
        gload_lds16(gA + k0,            lA);
        gload_lds16(gA + k0 + 16 * HD,  lA + 512);
        gload_lds16(gB + k0,            lB);
        gload_lds16(gB + k0 + 16 * HD,  lB + 512);
        __syncthreads();                 // drains vmcnt -> LDS tile ready

        bf16x8 af[4], bfr[4];
#pragma unroll
        for (int t = 0; t < 4; ++t) {
            af[t]  = *(const bf16x8*)(As + (wm * 64 + t * 16 + l15) * 32 + quad * 8);
            bfr[t] = *(const bf16x8*)(Bs + (wn * 64 + t * 16 + l15) * 32 + quad * 8);
        }
#pragma unroll
        for (int i = 0; i < 4; ++i)
#pragma unroll
            for (int j = 0; j < 4; ++j)
                acc[i][j] = __builtin_amdgcn_mfma_f32_16x16x32_bf16(
                    af[i], bfr[j], acc[i][j], 0, 0, 0);
        __syncthreads();                 // before next-iter overwrite
    }

    // Epilogue: bias + RoPE + scatter. C/D: col=lane&15, row=quad*4+reg.
    // mrow_base..+3 never cross a 2048 (batch) boundary: hoist bb/sb.
#pragma unroll
    for (int i = 0; i < 4; ++i) {
        const int mrow_base = m0 + wm * 64 + i * 16 + quad * 4;
        const int bb = mrow_base >> 11;
        const int sb = mrow_base & (S_LEN - 1);
#pragma unroll
        for (int j = 0; j < 2; ++j) {
            const int n1 = n0 + wn * 64 + j * 16 + l15;    // dim in [0,32)
            const int n2 = n1 + 32;
            const float b1 = bias[n1];
            const float b2 = bias[n2];
            const int which = n1 >> 10;          // 0=q 1=k 2=v (block-uniform)
            const int hd    = n1 & 1023;
            const int head  = hd >> 6;
            const int dim   = hd & 63;           // < 32 by construction
            if (which == 2) {
                // V: no RoPE; write transposed [b][h][d][s], bf16x4 over r.
                bf16x4 v1, v2;
#pragma unroll
                for (int r = 0; r < 4; ++r) {
                    v1[r] = f2bf(acc[i][j][r]     + b1);
                    v2[r] = f2bf(acc[i][j + 2][r] + b2);
                }
                const size_t off = ((size_t)(bb * NHEAD + head) * DHEAD + dim) * S_LEN + sb;
                *(bf16x4*)(vws + off)                        = v1;
                *(bf16x4*)(vws + off + (size_t)32 * S_LEN)   = v2;
            } else {
                const float inv_freq = __expf(-(float)dim * 0.28782313662425572f);
                bf16_t* outp = (which == 0) ? qws : kws;
#pragma unroll
                for (int r = 0; r < 4; ++r) {
                    const int s = sb + r;
                    float x1 = acc[i][j][r]     + b1;
                    float x2 = acc[i][j + 2][r] + b2;
                    const float ang = (float)s * inv_freq;
                    float cs = __cosf(ang);
                    float sn = __sinf(ang);
                    if (which == 1) { cs *= QKSCALE; sn *= QKSCALE; }
                    const float o1 = x1 * cs - x2 * sn;
                    const float o2 = x2 * cs + x1 * sn;
                    const size_t off = ((size_t)(bb * NHEAD + head) * S_LEN + s) * DHEAD + dim;
                    outp[off]      = f2bf(o1);
                    outp[off + 32] = f2bf(o2);
                }
            }
        }
    }
}

// ---------------------------------------------------------------------------
// Kernel 2 (unchanged this round): flash attention, operand-swapped QK^T.
// Round-2 counters: MfmaUtil 15.2 / VALUBusy 39 / HBM 4% / Occ 28% ->
// still latency-bound; next lever is killing the Ps LDS round-trip
// (separate experiment).
// ---------------------------------------------------------------------------
#define STK 72
#define STP 72

__global__ __launch_bounds__(256, 3)
void attn_kernel(const bf16_t* __restrict__ qws, const bf16_t* __restrict__ kws,
                 const bf16_t* __restrict__ vtws, float* __restrict__ out)
{
    __shared__ bf16_t Ks[2][64 * STK]; // 2 x 9216 B  K [t][d], double-buffered
    __shared__ bf16_t Ps[128 * STP];   // 18432 B P [q][t], wave-private rows

    const int tid  = threadIdx.x;
    const int wave = tid >> 6;
    const int lane = tid & 63;
    const int l15  = lane & 15;
    const int quad = lane >> 4;
    const int bh   = blockIdx.x;          // 0..63  (XCD = bh % 8)
    const int qt   = blockIdx.y;          // 0..15
    const size_t baseS = (size_t)bh * S_LEN * DHEAD;   // q/k [s][d]; vt [d][s]
    const int q0 = qt * 128 + wave * 32;

    // Q fragments (B-operand: n=q on lane&15, k=d on quad*8+j), persistent.
    bf16x8 aq[2][2];
#pragma unroll
    for (int qsub = 0; qsub < 2; ++qsub)
#pragma unroll
        for (int kb = 0; kb < 2; ++kb)
            aq[qsub][kb] = *(const bf16x8*)(qws + baseS +
                (size_t)(q0 + qsub * 16 + l15) * DHEAD + kb * 32 + quad * 8);

    // K staging coords: 64 t-rows x 64 d-cols, 2 x uint4 per thread
    const int srow = tid >> 2;            // t
    const int scol = (tid & 3) * 8;       // d base
    const bf16_t* kstage = kws + baseS + (size_t)srow * DHEAD + scol;
    const bf16_t* vtbase = vtws + baseS + quad * 8;

    // Prologue: tile 0 -> Ks[0]; tile 1 -> kreg; one barrier.
    uint4 kreg[2];
#pragma unroll
    for (int jj = 0; jj < 2; ++jj)
        kreg[jj] = *(const uint4*)(kstage + jj * 32);
#pragma unroll
    for (int jj = 0; jj < 2; ++jj)
        *(uint4*)(&Ks[0][0] + srow * STK + scol + jj * 32) = kreg[jj];
#pragma unroll
    for (int jj = 0; jj < 2; ++jj)
        kreg[jj] = *(const uint4*)(kstage + 64 * DHEAD + jj * 32);
    __syncthreads();

    float m_i[2] = {-1e30f, -1e30f};      // per-lane state for q = qsub*16+l15
    float l_i[2] = {0.f, 0.f};            // (replicated across quads)
    floatx4 o_acc[2][4];
#pragma unroll
    for (int qsub = 0; qsub < 2; ++qsub)
#pragma unroll
        for (int dt = 0; dt < 4; ++dt)
            o_acc[qsub][dt] = (floatx4){0.f, 0.f, 0.f, 0.f};

    for (int kt = 0; kt < 32; ++kt) {
        const int cur = kt & 1;

        // --- V fragments for THIS iter: issue first, consume at PV ---------
        bf16x8 bv[2][4];
#pragma unroll
        for (int kb = 0; kb < 2; ++kb)
#pragma unroll
            for (int dt = 0; dt < 4; ++dt)
                bv[kb][dt] = *(const bf16x8*)(vtbase +
                    (size_t)(dt * 16 + l15) * S_LEN + kt * 64 + kb * 32);

        // --- S^T = K Q^T : C row = t (quad*4+r), col = q (l15) -------------
        floatx4 st[2][4];
#pragma unroll
        for (int qsub = 0; qsub < 2; ++qsub)
#pragma unroll
            for (int mt = 0; mt < 4; ++mt)
                st[qsub][mt] = (floatx4){0.f, 0.f, 0.f, 0.f};
#pragma unroll
        for (int kb = 0; kb < 2; ++kb)
#pragma unroll
            for (int mt = 0; mt < 4; ++mt) {
                bf16x8 ak = *(const bf16x8*)(&Ks[cur][0] + (mt * 16 + l15) * STK + kb * 32 + quad * 8);
#pragma unroll
                for (int qsub = 0; qsub < 2; ++qsub)
                    st[qsub][mt] = __builtin_amdgcn_mfma_f32_16x16x32_bf16(
                        ak, aq[qsub][kb], st[qsub][mt], 0, 0, 0);
            }

        // --- stage tile kt+1 into other buffer; prefetch tile kt+2 ---------
        if (kt + 1 < 32) {
#pragma unroll
            for (int jj = 0; jj < 2; ++jj)
                *(uint4*)(&Ks[cur ^ 1][0] + srow * STK + scol + jj * 32) = kreg[jj];
            if (kt + 2 < 32) {
#pragma unroll
                for (int jj = 0; jj < 2; ++jj)
                    kreg[jj] = *(const uint4*)(kstage + (size_t)(kt + 2) * 64 * DHEAD + jj * 32);
            }
        }

        // --- online softmax: lane owns q = qsub*16+l15, 16 t-values local --
#pragma unroll
        for (int qsub = 0; qsub < 2; ++qsub) {
            floatx4 m01 = fmax4(st[qsub][0], st[qsub][1]);
            floatx4 m23 = fmax4(st[qsub][2], st[qsub][3]);
            floatx4 mm  = fmax4(m01, m23);
            float mx = fmaxf(fmaxf(mm[0], mm[1]), fmaxf(mm[2], mm[3]));
            mx = fmaxf(mx, __shfl_xor(mx, 16, 64));
            mx = fmaxf(mx, __shfl_xor(mx, 32, 64));

            // defer-rescale: keep old running max while growth <= 8 (base-2
            // units -> P bounded by 2^8 = 256, fine in bf16/f32). First iter
            // always rescales (m_i = -1e30). Wave-uniform branch via __all.
            const bool noresc = __all(mx - m_i[qsub] <= 8.0f) != 0;
            float mref, alpha;
            if (noresc) {
                mref = m_i[qsub];
            } else {
                mref = fmaxf(m_i[qsub], mx);
                alpha = fexp2(m_i[qsub] - mref);
                m_i[qsub] = mref;
            }

            float rs = 0.f;
#pragma unroll
            for (int mt = 0; mt < 4; ++mt) {
                bf16x4 pb;
#pragma unroll
                for (int r = 0; r < 4; ++r) {
                    const float p = fexp2(st[qsub][mt][r] - mref);
                    pb[r] = f2bf(p);
                    rs += bf2f(pb[r]);
                }
                *(bf16x4*)(Ps + (wave * 32 + qsub * 16 + l15) * STP + mt * 16 + quad * 4) = pb;
            }
            rs += __shfl_xor(rs, 16, 64);
            rs += __shfl_xor(rs, 32, 64);

            if (noresc) {
                l_i[qsub] += rs;
            } else {
                l_i[qsub] = l_i[qsub] * alpha + rs;
                // rescale O: alpha moved to C-layout rows via one shfl per r
#pragma unroll
                for (int r = 0; r < 4; ++r) {
                    const float a = __shfl(alpha, (lane & 48) | (quad * 4 + r), 64);
#pragma unroll
                    for (int dt = 0; dt < 4; ++dt)
                        o_acc[qsub][dt][r] *= a;
                }
            }
        }

        // --- O += P V : A = P [q][t] (b128), B = V^T fragments (global) ----
#pragma unroll
        for (int kb = 0; kb < 2; ++kb) {
#pragma unroll
            for (int qsub = 0; qsub < 2; ++qsub) {
                bf16x8 ap = *(const bf16x8*)(Ps + (wave * 32 + qsub * 16 + l15) * STP + kb * 32 + quad * 8);
#pragma unroll
                for (int dt = 0; dt < 4; ++dt)
                    o_acc[qsub][dt] = __builtin_amdgcn_mfma_f32_16x16x32_bf16(
                        ap, bv[kb][dt], o_acc[qsub][dt], 0, 0, 0);
            }
        }
        if (kt + 1 < 32) __syncthreads();
    }

    // normalize + store out[b][s][h*64+d] (fp32); l transposed via shfl
    const int bb = bh >> 4, hh = bh & 15;
#pragma unroll
    for (int qsub = 0; qsub < 2; ++qsub)
#pragma unroll
        for (int r = 0; r < 4; ++r) {
            const float lv  = __shfl(l_i[qsub], (lane & 48) | (quad * 4 + r), 64);
            const float inv = 1.0f / lv;
            const int s = q0 + qsub * 16 + quad * 4 + r;
            const size_t off0 = ((size_t)(bb * S_LEN + s)) * HD + hh * DHEAD;
#pragma unroll
            for (int dt = 0; dt < 4; ++dt)
                out[off0 + dt * 16 + l15] = o_acc[qsub][dt][r] * inv;
        }
}

extern "C" void kernel_launch(void* const* d_in, const int* in_sizes, int n_in,
                              void* d_out, int out_size, void* d_ws, size_t ws_size,
                              hipStream_t stream) {
    const float* X    = (const float*)d_in[0];   // (4,2048,1024) fp32
    const float* W    = (const float*)d_in[1];   // (3072,1024) fp32
    const float* bias = (const float*)d_in[2];   // (3072,) fp32
    float* out = (float*)d_out;                  // (4,2048,1024) fp32

    const size_t per = (size_t)B_SZ * NHEAD * S_LEN * DHEAD;   // 8.39M elems
    bf16_t* qws = (bf16_t*)d_ws;
    bf16_t* kws = qws + per;
    bf16_t* vws = kws + per;                     // holds V^T [b][h][d][s]

    // bf16 copies of X and W live in the out buffer as scratch (23.1 MB of
    // 33.5 MB); consumed by the GEMM, clobbered later by attn's real output.
    bf16_t* Xb = (bf16_t*)out;
    bf16_t* Wb = Xb + (size_t)NXELEM;

    cvt_kernel<<<dim3(4096), 256, 0, stream>>>(X, W, Xb, Wb);
    qkv_gemm_kernel<<<dim3(N3 / 128, M_ROWS / 128), 256, 0, stream>>>(
        Xb, Wb, bias, qws, kws, vws);
    attn_kernel<<<dim3(B_SZ * NHEAD, S_LEN / 128), 256, 0, stream>>>(
        qws, kws, vws, out);
}